// Round 1
// 247.413 us; speedup vs baseline: 1.1138x; 1.1138x over previous
//
#include <hip/hip_runtime.h>

#define HW  (512*512)

typedef _Float16 half8  __attribute__((__vector_size__(16)));
typedef _Float16 half4  __attribute__((__vector_size__(8)));
typedef _Float16 half2_t __attribute__((__vector_size__(4)));
typedef float    floatx4 __attribute__((__vector_size__(16)));
typedef float    floatx2 __attribute__((__vector_size__(8)));

__device__ __forceinline__ float gelu_f(float x){
    // gelu_tanh(x) = x * sigmoid(2c*(x + 0.044715 x^3)), c = sqrt(2/pi)
    // Only used to BUILD the per-block LUT now (256 evals/block total).
    float x2 = x * x;
    float q  = __builtin_fmaf(x2, -0.1029432f, -2.3022079f);
    float e  = __builtin_amdgcn_exp2f(x * q);
    return x * __builtin_amdgcn_rcpf(1.0f + e);
}

__device__ __forceinline__ float sigmoid_f(float x){
    float e = __builtin_amdgcn_exp2f(-1.44269504f * x);
    return __builtin_amdgcn_rcpf(1.0f + e);
}

// Trans-free GELU: piecewise-linear LUT, 256 intervals over [-8,8], entry =
// (slope a, intercept b) so g(x) ~= a*x + b.  5 full-rate VALU + 1 ds_read_b64
// per element vs 5 VALU + 2 quarter-rate trans for the exp/rcp form.
// Entry 0 has a~=0,b~=0 (extrapolates g=0 for x<-8); entry 255 has a~=1,b~=0
// (extrapolates g=x for x>8) -> clamping the BYTE OFFSET alone is sufficient.
__device__ __forceinline__ float glut_eval(const float* gl, float x){
    float p = __builtin_fmaf(x, 128.0f, 1024.0f);     // byte offset = 8*idx
    p = fminf(fmaxf(p, 0.0f), 2040.0f);               // v_med3_f32
    unsigned off = ((unsigned)p) & 0xFFFFFFF8u;       // 8B-align (b64 read)
    floatx2 ab = *(const floatx2*)((const char*)gl + off);
    return __builtin_fmaf(ab[0], x, ab[1]);
}

// act layout: element (px, n) lives at f16 offset px*256 + ((n>>3) ^ (px&7))*8 + (n&7).
// 3-bit chunk XOR keeps b128 B-frag reads 8-lane/4-bank balanced and b64
// epilogue writes at optimal 4 accesses/bank (verified analytically).

// ---------------- prep: coalesced weight pack + per-batch c0 ----------
// Packed block (ks, mt) element at lane*8+j  <->  W[k=ks*32+(lane>>4)*8+j][n_out=mt*16+(lane&15)]
// Serves as the MFMA *A* operand now (A[m=n_out=ln15][k=quad*8+j]) — same bytes as before.
__global__ void prep_all(const float* __restrict__ W1, const float* __restrict__ W2,
                         const float* __restrict__ W3, const float* __restrict__ emb,
                         const int* __restrict__ sidx, const float* __restrict__ W0,
                         const float* __restrict__ b0,
                         _Float16* __restrict__ wp, float* __restrict__ c0){
    __shared__ float ld[32][68];          // stride 68: 16B-aligned rows, bank-rotated
    int blk = blockIdx.x;
    int tid = threadIdx.x;
    if (blk < 64){
        int mat = blk >> 5;               // 0 = W1, 1 = W2
        int g   = blk & 31;
        int ks  = g >> 2;                 // 0..7
        int ntq = g & 3;                  // 0..3
        const float* W = mat ? W2 : W1;
        int row = tid >> 3;               // 0..31
        int c8  = (tid & 7) * 8;          // 0..56
        const float* src = &W[(ks*32 + row)*256 + ntq*64 + c8];
        *(floatx4*)&ld[row][c8]     = *(const floatx4*)src;
        *(floatx4*)&ld[row][c8 + 4] = *(const floatx4*)(src + 4);
        __syncthreads();
        int lane = tid & 63;
        int nt_l = tid >> 6;              // 0..3
        half8 h;
        #pragma unroll
        for (int j = 0; j < 8; j++)
            h[j] = (_Float16)ld[(lane >> 4)*8 + j][nt_l*16 + (lane & 15)];
        _Float16* dst = wp + mat*65536 + (ks*16 + ntq*4 + nt_l)*512 + lane*8;
        *(half8*)dst = h;
    } else if (blk < 80){
        int i    = (blk - 64)*256 + tid;  // W3 padded [256][16]
        int j    = i & 7;
        int lane = (i >> 3) & 63;
        int ks   = i >> 9;
        int k = ks*32 + ((lane >> 4) << 3) + j;
        int n = lane & 15;
        wp[131072 + i] = (_Float16)((n < 3) ? W3[k*3 + n] : 0.0f);
    } else {
        int b = blk - 80;
        int s = sidx[b];
        float acc = b0[tid];
        #pragma unroll 8
        for (int d = 0; d < 64; d++)
            acc = fmaf(emb[s*64 + d], W0[(3 + d)*256 + tid], acc);
        c0[b*256 + tid] = acc;
    }
}

// ---------------- fused MLP: 64-pixel tile, 256 threads (4 waves) ----------
// Hidden layers compute D = Wpacked(A) * act(B): D rows = output neurons,
// D cols = pixels -> each lane holds 4 consecutive neurons of one pixel ->
// epilogue is ds_write_b64 instead of 4x ds_write_b16.
__global__ __launch_bounds__(256, 4)
void nilut_main(const float* __restrict__ rgb,
                const float* __restrict__ W0,
                const float* __restrict__ b1v,
                const float* __restrict__ b2v,
                const float* __restrict__ b3v,
                const _Float16* __restrict__ wp,
                const float* __restrict__ c0,
                float* __restrict__ out){
    __shared__ __align__(16) _Float16 act[64 * 256];    // 32768 B, chunk-XOR swizzled
    __shared__ __align__(16) float    w0s[1024];        // W0 rows 0..2 | c0[b]; reused as out bounce
    __shared__ __align__(16) float    rgbs[192];        // staged rgb tile [3][64]
    __shared__ __align__(16) float    glut[512];        // 256 x (slope,intercept) gelu LUT, 2 KiB

    const int tid = threadIdx.x;
    const int wg  = blockIdx.x;
    const int pixbase = wg * 64;
    const int b   = pixbase >> 18;        // HW = 2^18
    const int hw0 = pixbase & (HW - 1);

    // stage W0[0:3] + c0[b] into LDS
    #pragma unroll
    for (int r = 0; r < 4; r++){
        int q = r*256 + tid;
        w0s[q] = (q < 768) ? W0[q] : c0[b*256 + (q - 768)];
    }
    // stage rgb tile (3 runs of 64 contiguous floats)
    if (tid < 192){
        int c = tid >> 6, row = tid & 63;
        rgbs[tid] = rgb[b*3*HW + c*HW + hw0 + row];
    }
    // build gelu LUT: thread t owns interval [x0, x0+1/16).  Intercept is
    // computed against the ROUNDED slope so endpoints stay exact.
    {
        float x0 = -8.0f + (float)tid * 0.0625f;
        float g0 = gelu_f(x0);
        float g1 = gelu_f(x0 + 0.0625f);
        float a  = (g1 - g0) * 16.0f;
        float bb = __builtin_fmaf(-a, x0, g0);
        floatx2 ab = {a, bb};
        *(floatx2*)&glut[2*tid] = ab;
    }
    __syncthreads();

    // ---- layer 0: coeffs in registers, 8 cols x 8 rows per thread ----
    // float2 vectors -> v_pk_fma_f32 (full-rate packed) halves the fma count.
    {
        int ng = tid & 31;                // chunk index: cols ng*8 .. ng*8+7
        int rg = tid >> 5;                // row group 0..7
        floatx2 cw2[4][4];
        #pragma unroll
        for (int p = 0; p < 4; p++){
            const floatx2* w2 = (const floatx2*)&w0s[p*256 + ng*8];
            #pragma unroll
            for (int q = 0; q < 4; q++) cw2[p][q] = w2[q];
        }
        #pragma unroll
        for (int hf = 0; hf < 2; hf++){
            floatx4 rv[3];
            #pragma unroll
            for (int c = 0; c < 3; c++)
                rv[c] = *(const floatx4*)&rgbs[c*64 + rg*8 + hf*4];
            #pragma unroll
            for (int r4 = 0; r4 < 4; r4++){
                int row = rg*8 + hf*4 + r4;
                floatx2 rr2 = {rv[0][r4], rv[0][r4]};
                floatx2 gg2 = {rv[1][r4], rv[1][r4]};
                floatx2 bb2 = {rv[2][r4], rv[2][r4]};
                half8 v;
                #pragma unroll
                for (int j2 = 0; j2 < 4; j2++){
                    floatx2 z2 = rr2*cw2[0][j2] + (gg2*cw2[1][j2] + (bb2*cw2[2][j2] + cw2[3][j2]));
                    half2_t g = __builtin_amdgcn_cvt_pkrtz(glut_eval(glut, z2[0]),
                                                           glut_eval(glut, z2[1]));
                    v[2*j2]   = g[0];
                    v[2*j2+1] = g[1];
                }
                *(half8*)&act[row*256 + ((ng ^ (row & 7)) << 3)] = v;
            }
        }
    }
    __syncthreads();

    const int lane = tid & 63;
    const int wv   = tid >> 6;            // 0..3
    const int ln15 = lane & 15;
    const int quad = lane >> 4;
    const int qr   = quad * 4;
    const int sx   = ln15 & 7;            // swizzle key (px & 7)
    const int qx8  = (quad ^ (sx & 3)) * 8;
    const int kb32 = ((sx >> 2) & 1) << 5;   // k-chunk XOR bit, f16 units

    // B-frag (act) read base per pixel tile: addr = pbq[pt] + ((ks<<5) ^ kb32)
    int pbq[4];
    #pragma unroll
    for (int pt = 0; pt < 4; pt++)
        pbq[pt] = (pt*16 + ln15)*256 + qx8;

    // epilogue write: addr = eb[pt] + cx[mtl] (b64, 4 consecutive neurons)
    const int qh = quad >> 1, qs = (quad & 1) * 4;
    int eb[4];
    #pragma unroll
    for (int pt = 0; pt < 4; pt++)
        eb[pt] = (pt*16 + ln15)*256 + qs;

    // ---- layers 1 and 2: D = W(A) x act(B), wave wv owns n_out tiles wv*4..+3 ----
    const _Float16* wl  = wp;             // Wp1
    const float* bias   = b1v;
    #pragma unroll 1
    for (int L = 0; L < 2; L++){
        floatx4 acc[4][4];                // [pt][mtl]
        #pragma unroll
        for (int mtl = 0; mtl < 4; mtl++){
            floatx4 bv = *(const floatx4*)&bias[(wv*4 + mtl)*16 + qr];
            #pragma unroll
            for (int pt = 0; pt < 4; pt++)
                acc[pt][mtl] = bv;
        }

        const half8* wp8 = (const half8*)wl;
        #pragma unroll 2
        for (int ks = 0; ks < 8; ks++){
            int t = (ks << 5) ^ kb32;
            half8 bfr[4];
            #pragma unroll
            for (int pt = 0; pt < 4; pt++)
                bfr[pt] = *(const half8*)&act[pbq[pt] + t];
            #pragma unroll
            for (int mtl = 0; mtl < 4; mtl++){
                half8 af = wp8[(ks*16 + wv*4 + mtl)*64 + lane];
                #pragma unroll
                for (int pt = 0; pt < 4; pt++)
                    acc[pt][mtl] = __builtin_amdgcn_mfma_f32_16x16x32_f16(af, bfr[pt], acc[pt][mtl], 0, 0, 0);
            }
        }
        __syncthreads();   // all reads of act done before overwrite
        #pragma unroll
        for (int mtl = 0; mtl < 4; mtl++){
            int cx = (((wv*4 + mtl)*2 + qh) ^ sx) << 3;
            #pragma unroll
            for (int pt = 0; pt < 4; pt++){
                floatx4 v = acc[pt][mtl];
                half2_t g01 = __builtin_amdgcn_cvt_pkrtz(glut_eval(glut, v[0]),
                                                         glut_eval(glut, v[1]));
                half2_t g23 = __builtin_amdgcn_cvt_pkrtz(glut_eval(glut, v[2]),
                                                         glut_eval(glut, v[3]));
                half4 h;
                h[0] = g01[0]; h[1] = g01[1]; h[2] = g23[0]; h[3] = g23[1];
                *(half4*)&act[eb[pt] + cx] = h;
            }
        }
        __syncthreads();
        wl = wp + 65536;   // Wp2
        bias = b2v;
    }

    // ---- final layer 256 -> 3 (padded to 16) + sigmoid ----
    {
        const half8* wp8 = (const half8*)(wp + 131072);
        floatx4 ac = (floatx4){0.f,0.f,0.f,0.f};
        int pb = (wv*16 + ln15)*256 + qx8;   // this wave's pixel tile
        #pragma unroll
        for (int ks = 0; ks < 8; ks++){
            half8 bfr = *(const half8*)&act[pb + ((ks << 5) ^ kb32)];
            half8 af  = wp8[ks*64 + lane];
            ac = __builtin_amdgcn_mfma_f32_16x16x32_f16(af, bfr, ac, 0, 0, 0);
        }
        // D rows = channel (qr+r), col = pixel ln15; only quad 0 rows 0..2 valid.
        // w0s dead since layer 0 -> reuse as out bounce [3][64]
        if (quad == 0){
            #pragma unroll
            for (int r = 0; r < 3; r++)
                w0s[r*64 + wv*16 + ln15] = sigmoid_f(ac[r] + b3v[r]);
        }
        __syncthreads();
        if (tid < 48){
            int c  = tid >> 4;
            int i2 = tid & 15;
            float4* dst = (float4*)(out + (b*3 + c)*HW + hw0);
            dst[i2] = ((float4*)(w0s + c*64))[i2];
        }
    }
}

extern "C" void kernel_launch(void* const* d_in, const int* in_sizes, int n_in,
                              void* d_out, int out_size, void* d_ws, size_t ws_size,
                              hipStream_t stream){
    const float* rgb = (const float*)d_in[0];
    const int*  sidx = (const int*) d_in[1];
    const float* emb = (const float*)d_in[2];
    const float* W0  = (const float*)d_in[3];
    const float* b0  = (const float*)d_in[4];
    const float* W1  = (const float*)d_in[5];
    const float* b1  = (const float*)d_in[6];
    const float* W2  = (const float*)d_in[7];
    const float* b2  = (const float*)d_in[8];
    const float* W3  = (const float*)d_in[9];
    const float* b3  = (const float*)d_in[10];
    float* out = (float*)d_out;

    _Float16* wp = (_Float16*)d_ws;                    // 135168 f16 = 270336 B
    float*    c0 = (float*)((char*)d_ws + 270336);     // 512 f32

    int n_pix = in_sizes[0] / 3;                       // 524288
    prep_all<<<82, 256, 0, stream>>>(W1, W2, W3, emb, sidx, W0, b0, wp, c0);
    nilut_main<<<n_pix / 64, 256, 0, stream>>>(rgb, W0, b1, b2, b3, wp, c0, out);
}